// Round 1
// baseline (121.334 us; speedup 1.0000x reference)
//
#include <hip/hip_runtime.h>
#include <stdint.h>

// Problem constants (fixed by the reference)
#define NB    32768   // batch
#define NS    16      // states per element
#define SS    32      // state size (K of stage 1)
#define ENCD  64      // encoder width
#define HIDD  128     // hidden width
#define OUTD  8       // output logits
#define BT    16      // batch elements per block
#define THREADS 256   // 4 waves

// Workspace layout (units: _Float16 elements). Weights pre-transposed to
// fragment order (N-major, K-minor) and pre-split into fp16 hi/lo so the
// main kernel loads each MFMA B-fragment as ONE 16B half8 load.
#define WENC_HI 0         // [64][32]   e-major
#define WENC_LO 2048
#define WF_HI   4096      // [128][128] h-major
#define WF_LO   20480
#define WDEC_HI 36864     // [16][128]  o-major, rows 8..15 zero-padded
#define WDEC_LO 38912
#define WS_HALVES 40960   // 80 KiB total

typedef _Float16 half8  __attribute__((ext_vector_type(8)));  // 8 f16 = 4 VGPRs
typedef __fp16   fp16x2 __attribute__((ext_vector_type(2)));  // cvt_pkrtz result type
typedef float    f32x4  __attribute__((ext_vector_type(4)));

#define MFMA(a, b, c) __builtin_amdgcn_mfma_f32_16x16x32_f16((a), (b), (c), 0, 0, 0)

// Split 8 floats into fp16 hi + lo: f = hi + lo + O(2^-20 |f|).
// Still used for A-side (activation) fragments only.
__device__ __forceinline__ void split8(const float* f, half8& hi, half8& lo) {
#pragma unroll
  for (int j = 0; j < 8; j += 2) {
    fp16x2 h  = __builtin_amdgcn_cvt_pkrtz(f[j], f[j + 1]);
    float  r0 = f[j]     - (float)h[0];
    float  r1 = f[j + 1] - (float)h[1];
    fp16x2 l2 = __builtin_amdgcn_cvt_pkrtz(r0, r1);
    hi[j] = (_Float16)(float)h[0];  hi[j + 1] = (_Float16)(float)h[1];
    lo[j] = (_Float16)(float)l2[0]; lo[j + 1] = (_Float16)(float)l2[1];
  }
}

// ---------------------------------------------------------------------------
// Prologue: transpose + hi/lo-split all weights once (runs in ~3 us).
// Replaces 12 per-thread split8 calls (~336 VALU ops) and 96 scalar loads
// in every one of 524288 main-kernel threads.
// ---------------------------------------------------------------------------
__global__ __launch_bounds__(256)
void presplit_w(const float* __restrict__ W_enc,
                const float* __restrict__ W_f,
                const float* __restrict__ W_dec,
                _Float16* __restrict__ ws)
{
  const int idx = blockIdx.x * 256 + threadIdx.x;   // grid sized to 20480 exactly
  float v; int hi_off, lo_off;
  if (idx < 2048) {                      // W_enc^T [e][k]
    const int e = idx >> 5, k = idx & 31;
    v = W_enc[k * ENCD + e];
    hi_off = WENC_HI + idx; lo_off = WENC_LO + idx;
  } else if (idx < 2048 + 16384) {       // W_f^T [h][k]
    const int j = idx - 2048, h = j >> 7, k = j & 127;
    v = W_f[k * HIDD + h];
    hi_off = WF_HI + j; lo_off = WF_LO + j;
  } else {                               // W_dec^T [o][k], padded N 8->16
    const int j = idx - 18432, o = j >> 7, k = j & 127;
    v = (o < OUTD) ? W_dec[k * OUTD + o] : 0.f;
    hi_off = WDEC_HI + j; lo_off = WDEC_LO + j;
  }
  const _Float16 h = (_Float16)v;              // RTN hi
  const _Float16 l = (_Float16)(v - (float)h); // residual lo
  ws[hi_off] = h;
  ws[lo_off] = l;
}

// ---------------------------------------------------------------------------
// Main fused kernel
// ---------------------------------------------------------------------------
__global__ __launch_bounds__(THREADS, 5)   // ~102 VGPR cap: fits 32-reg obs stage
void gnn_fused(const float* __restrict__ obs,
               const _Float16* __restrict__ wsp,
               const float* __restrict__ b_enc,
               const float* __restrict__ b_f,
               const float* __restrict__ b_dec,
               float* __restrict__ out)
{
  // stride 132 floats: rows 528 B (16B-aligned), row-to-row bank shift of 4
  __shared__ __align__(16) float f_in[BT][132];   // stage-2 output [batch][128]
  __shared__ __align__(16) float hidn[BT][132];   // stage-3 output [batch][128]

  const int tid  = threadIdx.x;
  const int w    = tid >> 6;     // wave 0..3
  const int l    = tid & 63;     // lane
  const int m15  = l & 15;
  const int quad = l >> 4;
  const int b0   = blockIdx.x * BT;

  // ---- FIRST: issue ALL obs loads (8 x dwordx4/thread = whole block's input).
  // Deep vmcnt queue; everything below overlaps with HBM latency.
  const float* bp = obs + (size_t)(b0 + w * 4) * (NS * SS) + m15 * SS + quad * 8;
  float4 d0[4], d1[4];
#pragma unroll
  for (int i = 0; i < 4; ++i) {
    const float4* p = (const float4*)(bp + (size_t)i * (NS * SS));
    d0[i] = p[0];
    d1[i] = p[1];
  }

  // ---- stage-1 B-fragments: pre-split W_enc^T, one 16B load per fragment
  half8 we_hi[4], we_lo[4];
  float benc[4];
#pragma unroll
  for (int nt = 0; nt < 4; ++nt) {
    const int o = (nt * 16 + m15) * SS + quad * 8;
    we_hi[nt] = *(const half8*)(wsp + WENC_HI + o);
    we_lo[nt] = *(const half8*)(wsp + WENC_LO + o);
    benc[nt]  = b_enc[nt * 16 + m15];
  }

  // ================= stage 1 (enc MFMA) + stage 2 (masked mean-pool) =========
  // wave handles batches [b0 + w*4, b0 + w*4 + 4)
#pragma unroll
  for (int i = 0; i < 4; ++i) {
    float f[8] = {d0[i].x, d0[i].y, d0[i].z, d0[i].w,
                  d1[i].x, d1[i].y, d1[i].z, d1[i].w};

    // flags: lanes 0..15 hold states[b][n][0]; cumprod run length via ballot+ctz
    unsigned long long bal = __ballot((l < 16) && (f[0] == 1.0f));
    int run = __builtin_ctzll(~(bal >> 1));      // consecutive valid neighbors, 0..15
    float inv = 1.0f / fmaxf((float)run, 1.0f);

    half8 ahi, alo;
    split8(f, ahi, alo);

    const int bi = w * 4 + i;  // local batch row
#pragma unroll
    for (int nt = 0; nt < 4; ++nt) {
      f32x4 acc = {0.f, 0.f, 0.f, 0.f};
      acc = MFMA(ahi, we_hi[nt], acc);
      acc = MFMA(alo, we_hi[nt], acc);
      acc = MFMA(ahi, we_lo[nt], acc);
      // D layout: lane holds enc[n = quad*4 + r][e = nt*16 + m15]
      float s = 0.f, e0 = 0.f;
#pragma unroll
      for (int r = 0; r < 4; ++r) {
        int n = quad * 4 + r;
        float v = fmaxf(acc[r] + benc[nt], 0.f);
        if (n == 0) e0 = v;                    // agent row
        if (n >= 1 && n <= run) s += v;        // valid neighbor
      }
      s += __shfl_xor(s, 16, 64);              // reduce across quads
      s += __shfl_xor(s, 32, 64);
      if (quad == 0) {
        f_in[bi][nt * 16 + m15]      = e0;      // agent_enc
        f_in[bi][64 + nt * 16 + m15] = s * inv; // agg
      }
    }
  }
  __syncthreads();

  // ================= stage 3: hidden = relu(f_in @ W_f + b_f) ================
  // single 16-row M-tile; wave w covers N-tiles 2w, 2w+1 (32 of 128 h-columns)
  {
    half8 fa_hi[4], fa_lo[4];
#pragma unroll
    for (int ks = 0; ks < 4; ++ks) {
      const float4* p = (const float4*)&f_in[m15][ks * 32 + quad * 8];
      float4 a = p[0], b = p[1];
      float f[8] = {a.x, a.y, a.z, a.w, b.x, b.y, b.z, b.w};
      split8(f, fa_hi[ks], fa_lo[ks]);
    }

#pragma unroll
    for (int tt = 0; tt < 2; ++tt) {
      const int h0 = (w * 2 + tt) * 16 + m15;   // output column
      f32x4 acc = {0.f, 0.f, 0.f, 0.f};
#pragma unroll
      for (int ks = 0; ks < 4; ++ks) {
        const int o = h0 * HIDD + ks * 32 + quad * 8;   // W_f^T fragment, 16B
        half8 bhi = *(const half8*)(wsp + WF_HI + o);
        half8 blo = *(const half8*)(wsp + WF_LO + o);
        acc = MFMA(fa_hi[ks], bhi, acc);
        acc = MFMA(fa_lo[ks], bhi, acc);
        acc = MFMA(fa_hi[ks], blo, acc);
      }
      const float bfv = b_f[h0];
#pragma unroll
      for (int r = 0; r < 4; ++r)               // D: row = batch, col = h0
        hidn[quad * 4 + r][h0] = fmaxf(acc[r] + bfv, 0.f);
    }
  }
  __syncthreads();

  // ================= stage 4: logits = hidden @ W_dec + b_dec ================
  if (w == 0) {                                  // one 16-row M-tile
    half8 ga_hi[4], ga_lo[4];
#pragma unroll
    for (int ks = 0; ks < 4; ++ks) {
      const float4* p = (const float4*)&hidn[m15][ks * 32 + quad * 8];
      float4 a = p[0], b = p[1];
      float f[8] = {a.x, a.y, a.z, a.w, b.x, b.y, b.z, b.w};
      split8(f, ga_hi[ks], ga_lo[ks]);
    }
    f32x4 acc = {0.f, 0.f, 0.f, 0.f};
#pragma unroll
    for (int ks = 0; ks < 4; ++ks) {
      const int o = m15 * HIDD + ks * 32 + quad * 8;   // W_dec^T (zero-padded rows)
      half8 bhi = *(const half8*)(wsp + WDEC_HI + o);
      half8 blo = *(const half8*)(wsp + WDEC_LO + o);
      acc = MFMA(ga_hi[ks], bhi, acc);
      acc = MFMA(ga_lo[ks], bhi, acc);
      acc = MFMA(ga_hi[ks], blo, acc);
    }
    if (m15 < OUTD) {
      const float bd = b_dec[m15];
#pragma unroll
      for (int r = 0; r < 4; ++r) {
        const int m = quad * 4 + r;
        out[(size_t)(b0 + m) * OUTD + m15] = acc[r] + bd;
      }
    }
  }
}

extern "C" void kernel_launch(void* const* d_in, const int* in_sizes, int n_in,
                              void* d_out, int out_size, void* d_ws, size_t ws_size,
                              hipStream_t stream) {
  (void)in_sizes; (void)n_in; (void)ws_size; (void)out_size;
  const float* obs   = (const float*)d_in[0];
  const float* W_enc = (const float*)d_in[1];
  const float* b_enc = (const float*)d_in[2];
  const float* W_f   = (const float*)d_in[3];
  const float* b_f   = (const float*)d_in[4];
  const float* W_dec = (const float*)d_in[5];
  const float* b_dec = (const float*)d_in[6];
  float* out = (float*)d_out;
  _Float16* ws = (_Float16*)d_ws;

  // 20480 weight elements -> 80 blocks; re-split every launch (ws is re-poisoned)
  presplit_w<<<dim3(80), dim3(256), 0, stream>>>(W_enc, W_f, W_dec, ws);
  gnn_fused<<<dim3(NB / BT), dim3(THREADS), 0, stream>>>(obs, ws, b_enc, b_f,
                                                         b_dec, b_dec ? out : out);
}